// Round 1
// baseline (20759.831 us; speedup 1.0000x reference)
//
#include <hip/hip_runtime.h>

#define Nn 50000
#define Ee 600000
#define Hd 128
#define Ld 4
#define Kd 3

__device__ __forceinline__ float readlane_f(float v, int l) {
    return __int_as_float(__builtin_amdgcn_readlane(__float_as_int(v), l));
}

__global__ void zero_int_kernel(int* __restrict__ p, int n) {
    int i = blockIdx.x * blockDim.x + threadIdx.x;
    int stride = gridDim.x * blockDim.x;
    for (; i < n; i += stride) p[i] = 0;
}

__global__ void count_kernel(const int* __restrict__ col, int* __restrict__ deg) {
    int e = blockIdx.x * blockDim.x + threadIdx.x;
    if (e < Ee) atomicAdd(&deg[col[e]], 1);
}

// Single-block exclusive scan over deg -> starts[N+1]; also dinv = deg^-1/2.
__global__ void scan_kernel(const int* __restrict__ deg, int* __restrict__ starts,
                            float* __restrict__ dinv) {
    __shared__ int buf[1024];
    __shared__ int carry;
    if (threadIdx.x == 0) carry = 0;
    __syncthreads();
    for (int base = 0; base < Nn; base += 1024) {
        int i = base + threadIdx.x;
        int v = (i < Nn) ? deg[i] : 0;
        if (i < Nn) dinv[i] = (v > 0) ? rsqrtf((float)v) : 0.0f;
        buf[threadIdx.x] = v;
        __syncthreads();
        for (int off = 1; off < 1024; off <<= 1) {
            int t = (threadIdx.x >= off) ? buf[threadIdx.x - off] : 0;
            __syncthreads();
            buf[threadIdx.x] += t;
            __syncthreads();
        }
        if (i < Nn) starts[i] = carry + buf[threadIdx.x] - v;  // exclusive
        __syncthreads();
        if (threadIdx.x == 1023) carry += buf[1023];
        __syncthreads();
    }
    if (threadIdx.x == 0) starts[Nn] = carry;
}

__global__ void fill_kernel(const int* __restrict__ row, const int* __restrict__ col,
                            const int* __restrict__ starts, int* __restrict__ cnt,
                            const float* __restrict__ dinv,
                            int* __restrict__ eid_s, int* __restrict__ src_s,
                            float* __restrict__ w_s) {
    int e = blockIdx.x * blockDim.x + threadIdx.x;
    if (e < Ee) {
        int c = col[e], r = row[e];
        int slot = starts[c] + atomicAdd(&cnt[c], 1);
        eid_s[slot] = e;
        src_s[slot] = r;
        w_s[slot] = dinv[r] * dinv[c];
    }
}

// Fused edge MLP + scatter-free aggregation: one wave per target node.
// W1 in VGPRs (36/lane), W2 in LDS as paired float2, hidden via v_readlane.
// 4 edges batched per wave to amortize W2 LDS reads.
__global__ __launch_bounds__(256, 2) void edge_mlp_kernel(
    const float* __restrict__ x, const float* __restrict__ ea,
    const int* __restrict__ starts, const int* __restrict__ eid_s,
    const int* __restrict__ src_s,
    const float* __restrict__ eW1, const float* __restrict__ eb1,
    const float* __restrict__ eW2, const float* __restrict__ eb2,
    float* __restrict__ hout) {
    __shared__ float2 w2[Hd * 64];  // 64 KB: w2[k*64+l] = (W2[k][l], W2[k][l+64])
    for (int i = threadIdx.x; i < Hd * 64; i += 256) {
        int k = i >> 6, c = i & 63;
        w2[i] = make_float2(eW2[k * Hd + c], eW2[k * Hd + c + 64]);
    }
    __syncthreads();
    int lane = threadIdx.x & 63;
    float w1x[18], w1y[18];
#pragma unroll
    for (int j = 0; j < 18; ++j) {
        w1x[j] = eW1[j * Hd + lane];
        w1y[j] = eW1[j * Hd + lane + 64];
    }
    float b1x = eb1[lane], b1y = eb1[lane + 64];
    float b2x = eb2[lane], b2y = eb2[lane + 64];
    int wid = (blockIdx.x * 256 + threadIdx.x) >> 6;
    int nw = (gridDim.x * 256) >> 6;
    for (int node = wid; node < Nn; node += nw) {
        int s0 = starts[node], s1 = starts[node + 1];
        // target-node part of layer 1 is loop-invariant: fold into the bias
        float prex = b1x, prey = b1y;
#pragma unroll
        for (int j = 0; j < 7; ++j) {
            float xv = x[node * 7 + j];
            prex += xv * w1x[j];
            prey += xv * w1y[j];
        }
        float dcount = (float)(s1 - s0);
        float accx = dcount * b2x, accy = dcount * b2y;  // eb2 added once per edge
        for (int slot = s0; slot < s1; slot += 4) {
            float h0[4], h1[4];
#pragma unroll
            for (int u = 0; u < 4; ++u) {
                int sl = slot + u;
                if (sl < s1) {
                    int e = eid_s[sl];
                    int src = src_s[sl];
                    float a0 = prex, a1 = prey;
#pragma unroll
                    for (int j = 0; j < 7; ++j) {
                        float xv = x[src * 7 + j];
                        a0 += xv * w1x[7 + j];
                        a1 += xv * w1y[7 + j];
                    }
                    float4 ev = *(const float4*)&ea[e * 4];
                    a0 += ev.x * w1x[14] + ev.y * w1x[15] + ev.z * w1x[16] + ev.w * w1x[17];
                    a1 += ev.x * w1y[14] + ev.y * w1y[15] + ev.z * w1y[16] + ev.w * w1y[17];
                    h0[u] = fmaxf(a0, 0.0f);
                    h1[u] = fmaxf(a1, 0.0f);
                } else {
                    h0[u] = 0.0f;
                    h1[u] = 0.0f;
                }
            }
#pragma unroll 8
            for (int k = 0; k < 64; ++k) {
                float2 wA = w2[k * 64 + lane];
                float2 wB = w2[(k + 64) * 64 + lane];
#pragma unroll
                for (int u = 0; u < 4; ++u) {
                    float a = readlane_f(h0[u], k);
                    float b = readlane_f(h1[u], k);
                    accx += a * wA.x + b * wB.x;
                    accy += a * wA.y + b * wB.y;
                }
            }
        }
        hout[node * Hd + lane] = accx;
        hout[node * Hd + lane + 64] = accy;
    }
}

// C[i][c] = (acc ? C[i][c] : bias[c]) + A[i][:] @ W[:][c]; optional relu.
// Block: 4 waves x 8 rows; W staged in LDS as paired float2 (64 KB).
__global__ __launch_bounds__(256, 2) void gemm128_kernel(
    const float* __restrict__ A, const float* __restrict__ W,
    const float* __restrict__ bias, float* __restrict__ C,
    int accflag, int reluflag) {
    __shared__ float2 ws[Hd * 64];
    for (int i = threadIdx.x; i < Hd * 64; i += 256) {
        int k = i >> 6, c = i & 63;
        ws[i] = make_float2(W[k * Hd + c], W[k * Hd + c + 64]);
    }
    __syncthreads();
    int lane = threadIdx.x & 63;
    int wv = threadIdx.x >> 6;
    int row0 = (blockIdx.x * 4 + wv) * 8;
    float accx[8], accy[8];
#pragma unroll
    for (int r = 0; r < 8; ++r) {
        int rr = row0 + r;
        if (rr < Nn) {
            if (accflag) {
                accx[r] = C[rr * Hd + lane];
                accy[r] = C[rr * Hd + lane + 64];
            } else {
                accx[r] = bias[lane];
                accy[r] = bias[lane + 64];
            }
        } else {
            accx[r] = accy[r] = 0.0f;
        }
    }
    for (int k = 0; k < Hd; k += 4) {
        float4 a[8];
#pragma unroll
        for (int r = 0; r < 8; ++r) {
            int rr = min(row0 + r, Nn - 1);
            a[r] = *(const float4*)&A[rr * Hd + k];  // wave-broadcast load
        }
#pragma unroll
        for (int kk = 0; kk < 4; ++kk) {
            float2 w = ws[(k + kk) * 64 + lane];
#pragma unroll
            for (int r = 0; r < 8; ++r) {
                float av = (kk == 0) ? a[r].x : (kk == 1) ? a[r].y : (kk == 2) ? a[r].z : a[r].w;
                accx[r] += av * w.x;
                accy[r] += av * w.y;
            }
        }
    }
#pragma unroll
    for (int r = 0; r < 8; ++r) {
        int rr = row0 + r;
        if (rr < Nn) {
            float vx = accx[r], vy = accy[r];
            if (reluflag) { vx = fmaxf(vx, 0.0f); vy = fmaxf(vy, 0.0f); }
            C[rr * Hd + lane] = vx;
            C[rr * Hd + lane + 64] = vy;
        }
    }
}

// p_out[i] = sum over incoming edges of w[e] * p_in[src[e]]; wave per node.
__global__ void hop_kernel(const float* __restrict__ pin, float* __restrict__ pout,
                           const int* __restrict__ starts, const int* __restrict__ src_s,
                           const float* __restrict__ w_s) {
    int lane = threadIdx.x & 63;
    int wid = (blockIdx.x * blockDim.x + threadIdx.x) >> 6;
    int nw = (gridDim.x * blockDim.x) >> 6;
    for (int node = wid; node < Nn; node += nw) {
        int s0 = starts[node], s1 = starts[node + 1];
        float ax = 0.0f, ay = 0.0f;
        int slot = s0;
        for (; slot + 4 <= s1; slot += 4) {
            int r0 = src_s[slot], r1 = src_s[slot + 1], r2 = src_s[slot + 2], r3 = src_s[slot + 3];
            float w0 = w_s[slot], w1 = w_s[slot + 1], w2v = w_s[slot + 2], w3 = w_s[slot + 3];
            float2 v0 = *(const float2*)&pin[r0 * Hd + 2 * lane];
            float2 v1 = *(const float2*)&pin[r1 * Hd + 2 * lane];
            float2 v2 = *(const float2*)&pin[r2 * Hd + 2 * lane];
            float2 v3 = *(const float2*)&pin[r3 * Hd + 2 * lane];
            ax += w0 * v0.x + w1 * v1.x + w2v * v2.x + w3 * v3.x;
            ay += w0 * v0.y + w1 * v1.y + w2v * v2.y + w3 * v3.y;
        }
        for (; slot < s1; ++slot) {
            int r0 = src_s[slot];
            float w0 = w_s[slot];
            float2 v0 = *(const float2*)&pin[r0 * Hd + 2 * lane];
            ax += w0 * v0.x;
            ay += w0 * v0.y;
        }
        *(float2*)&pout[node * Hd + 2 * lane] = make_float2(ax, ay);
    }
}

__global__ void out_kernel(const float* __restrict__ hin, const float* __restrict__ oW,
                           const float* __restrict__ ob, float* __restrict__ y) {
    __shared__ float w[256];
    __shared__ float bb[2];
    w[threadIdx.x] = oW[threadIdx.x & 255];
    if (threadIdx.x < 2) bb[threadIdx.x] = ob[threadIdx.x];
    __syncthreads();
    int i = blockIdx.x * blockDim.x + threadIdx.x;
    if (i < Nn) {
        float a0 = bb[0], a1 = bb[1];
#pragma unroll
        for (int k = 0; k < Hd; k += 4) {
            float4 hv = *(const float4*)&hin[i * Hd + k];
            a0 += hv.x * w[2 * k] + hv.y * w[2 * k + 2] + hv.z * w[2 * k + 4] + hv.w * w[2 * k + 6];
            a1 += hv.x * w[2 * k + 1] + hv.y * w[2 * k + 3] + hv.z * w[2 * k + 5] + hv.w * w[2 * k + 7];
        }
        *(float2*)&y[i * 2] = make_float2(a0, a1);
    }
}

extern "C" void kernel_launch(void* const* d_in, const int* in_sizes, int n_in,
                              void* d_out, int out_size, void* d_ws, size_t ws_size,
                              hipStream_t stream) {
    const float* x    = (const float*)d_in[0];
    const int*   ei   = (const int*)d_in[1];
    const float* ea   = (const float*)d_in[2];
    const float* eW1  = (const float*)d_in[3];
    const float* eb1  = (const float*)d_in[4];
    const float* eW2  = (const float*)d_in[5];
    const float* eb2  = (const float*)d_in[6];
    const float* tagW = (const float*)d_in[7];
    const float* tagb = (const float*)d_in[8];
    const float* oW   = (const float*)d_in[9];
    const float* ob   = (const float*)d_in[10];
    float* y = (float*)d_out;
    const int* row = ei;        // source
    const int* col = ei + Ee;   // target

    char* wp = (char*)d_ws;
    auto carve = [&](size_t bytes) -> char* {
        char* p = wp;
        wp += (bytes + 15) & ~(size_t)15;
        return p;
    };
    int* deg     = (int*)carve((size_t)2 * Nn * 4);  // deg | cnt adjacent
    int* cnt     = deg + Nn;
    int* starts  = (int*)carve((size_t)(Nn + 1) * 4);
    float* dinv  = (float*)carve((size_t)Nn * 4);
    int* eid_s   = (int*)carve((size_t)Ee * 4);
    int* src_s   = (int*)carve((size_t)Ee * 4);
    float* w_s   = (float*)carve((size_t)Ee * 4);
    float* hbuf  = (float*)carve((size_t)Nn * Hd * 4);
    float* obuf  = (float*)carve((size_t)Nn * Hd * 4);
    float* pbuf  = (float*)carve((size_t)Nn * Hd * 4);
    float* p2buf = (float*)carve((size_t)Nn * Hd * 4);

    zero_int_kernel<<<400, 256, 0, stream>>>(deg, 2 * Nn);
    count_kernel<<<(Ee + 255) / 256, 256, 0, stream>>>(col, deg);
    scan_kernel<<<1, 1024, 0, stream>>>(deg, starts, dinv);
    fill_kernel<<<(Ee + 255) / 256, 256, 0, stream>>>(row, col, starts, cnt, dinv,
                                                      eid_s, src_s, w_s);
    edge_mlp_kernel<<<1024, 256, 0, stream>>>(x, ea, starts, eid_s, src_s,
                                              eW1, eb1, eW2, eb2, hbuf);

    for (int l = 0; l < Ld; ++l) {
        const float* Wl = tagW + (size_t)l * (Kd + 1) * Hd * Hd;
        gemm128_kernel<<<1563, 256, 0, stream>>>(hbuf, Wl, tagb + l * Hd, obuf, 0, 0);
        const float* pin = hbuf;
        float* pa = pbuf;
        float* pb = p2buf;
        for (int k = 1; k <= Kd; ++k) {
            hop_kernel<<<12500, 256, 0, stream>>>(pin, pa, starts, src_s, w_s);
            int relu = (k == Kd && l < Ld - 1) ? 1 : 0;
            gemm128_kernel<<<1563, 256, 0, stream>>>(pa, Wl + (size_t)k * Hd * Hd,
                                                     nullptr, obuf, 1, relu);
            pin = pa;
            float* t = pa; pa = pb; pb = t;
        }
        float* t = hbuf; hbuf = obuf; obuf = t;  // h = out (+relu already applied)
    }
    out_kernel<<<(Nn + 255) / 256, 256, 0, stream>>>(hbuf, oW, ob, y);
}

// Round 2
// 2001.087 us; speedup vs baseline: 10.3743x; 10.3743x over previous
//
#include <hip/hip_runtime.h>

#define Nn 50000
#define Ee 600000
#define Hd 128
#define Ld 4
#define Kd 3

__device__ __forceinline__ float readlane_f(float v, int l) {
    return __int_as_float(__builtin_amdgcn_readlane(__float_as_int(v), l));
}

__global__ void zero_int_kernel(int* __restrict__ p, int n) {
    int i = blockIdx.x * blockDim.x + threadIdx.x;
    int stride = gridDim.x * blockDim.x;
    for (; i < n; i += stride) p[i] = 0;
}

__global__ void count_kernel(const int* __restrict__ col, int* __restrict__ deg) {
    int e = blockIdx.x * blockDim.x + threadIdx.x;
    if (e < Ee) atomicAdd(&deg[col[e]], 1);
}

// Single-block exclusive scan over deg -> starts[N+1]; also dinv = deg^-1/2.
__global__ void scan_kernel(const int* __restrict__ deg, int* __restrict__ starts,
                            float* __restrict__ dinv) {
    __shared__ int buf[1024];
    __shared__ int carry;
    if (threadIdx.x == 0) carry = 0;
    __syncthreads();
    for (int base = 0; base < Nn; base += 1024) {
        int i = base + threadIdx.x;
        int v = (i < Nn) ? deg[i] : 0;
        if (i < Nn) dinv[i] = (v > 0) ? rsqrtf((float)v) : 0.0f;
        buf[threadIdx.x] = v;
        __syncthreads();
        for (int off = 1; off < 1024; off <<= 1) {
            int t = (threadIdx.x >= off) ? buf[threadIdx.x - off] : 0;
            __syncthreads();
            buf[threadIdx.x] += t;
            __syncthreads();
        }
        if (i < Nn) starts[i] = carry + buf[threadIdx.x] - v;  // exclusive
        __syncthreads();
        if (threadIdx.x == 1023) carry += buf[1023];
        __syncthreads();
    }
    if (threadIdx.x == 0) starts[Nn] = carry;
}

__global__ void fill_kernel(const int* __restrict__ row, const int* __restrict__ col,
                            const int* __restrict__ starts, int* __restrict__ cnt,
                            const float* __restrict__ dinv,
                            int* __restrict__ eid_s, int* __restrict__ src_s,
                            float* __restrict__ w_s) {
    int e = blockIdx.x * blockDim.x + threadIdx.x;
    if (e < Ee) {
        int c = col[e], r = row[e];
        int slot = starts[c] + atomicAdd(&cnt[c], 1);
        eid_s[slot] = e;
        src_s[slot] = r;
        w_s[slot] = dinv[r] * dinv[c];
    }
}

// Fused edge MLP + scatter-free aggregation: one wave per target node.
__global__ __launch_bounds__(256, 2) void edge_mlp_kernel(
    const float* __restrict__ x, const float* __restrict__ ea,
    const int* __restrict__ starts, const int* __restrict__ eid_s,
    const int* __restrict__ src_s,
    const float* __restrict__ eW1, const float* __restrict__ eb1,
    const float* __restrict__ eW2, const float* __restrict__ eb2,
    float* __restrict__ hout) {
    __shared__ float2 w2[Hd * 64];  // 64 KB: w2[k*64+l] = (W2[k][l], W2[k][l+64])
    for (int i = threadIdx.x; i < Hd * 64; i += 256) {
        int k = i >> 6, c = i & 63;
        w2[i] = make_float2(eW2[k * Hd + c], eW2[k * Hd + c + 64]);
    }
    __syncthreads();
    int lane = threadIdx.x & 63;
    float w1x[18], w1y[18];
#pragma unroll
    for (int j = 0; j < 18; ++j) {
        w1x[j] = eW1[j * Hd + lane];
        w1y[j] = eW1[j * Hd + lane + 64];
    }
    float b1x = eb1[lane], b1y = eb1[lane + 64];
    float b2x = eb2[lane], b2y = eb2[lane + 64];
    int wid = (blockIdx.x * 256 + threadIdx.x) >> 6;
    int nw = (gridDim.x * 256) >> 6;
    for (int node = wid; node < Nn; node += nw) {
        int s0 = starts[node], s1 = starts[node + 1];
        float prex = b1x, prey = b1y;
#pragma unroll
        for (int j = 0; j < 7; ++j) {
            float xv = x[node * 7 + j];
            prex += xv * w1x[j];
            prey += xv * w1y[j];
        }
        float dcount = (float)(s1 - s0);
        float accx = dcount * b2x, accy = dcount * b2y;
        for (int slot = s0; slot < s1; slot += 4) {
            float h0[4], h1[4];
#pragma unroll
            for (int u = 0; u < 4; ++u) {
                int sl = slot + u;
                if (sl < s1) {
                    int e = eid_s[sl];
                    int src = src_s[sl];
                    float a0 = prex, a1 = prey;
#pragma unroll
                    for (int j = 0; j < 7; ++j) {
                        float xv = x[src * 7 + j];
                        a0 += xv * w1x[7 + j];
                        a1 += xv * w1y[7 + j];
                    }
                    float4 ev = *(const float4*)&ea[e * 4];
                    a0 += ev.x * w1x[14] + ev.y * w1x[15] + ev.z * w1x[16] + ev.w * w1x[17];
                    a1 += ev.x * w1y[14] + ev.y * w1y[15] + ev.z * w1y[16] + ev.w * w1y[17];
                    h0[u] = fmaxf(a0, 0.0f);
                    h1[u] = fmaxf(a1, 0.0f);
                } else {
                    h0[u] = 0.0f;
                    h1[u] = 0.0f;
                }
            }
#pragma unroll 8
            for (int k = 0; k < 64; ++k) {
                float2 wA = w2[k * 64 + lane];
                float2 wB = w2[(k + 64) * 64 + lane];
#pragma unroll
                for (int u = 0; u < 4; ++u) {
                    float a = readlane_f(h0[u], k);
                    float b = readlane_f(h1[u], k);
                    accx += a * wA.x + b * wB.x;
                    accy += a * wA.y + b * wB.y;
                }
            }
        }
        hout[node * Hd + lane] = accx;
        hout[node * Hd + lane + 64] = accy;
    }
}

// Fused per-layer TAG GEMM: C = P0@W0 + P1@W1 + P2@W2 + P3@W3 + bias (opt relu).
// 128x128 block tile, BK=16, 256 threads, 8x8 micro-tile per thread.
// A-tile transposed in LDS (As[k][row]) for conflict-free b128 reads.
__global__ __launch_bounds__(256, 3) void tag_gemm_kernel(
    const float* __restrict__ P0, const float* __restrict__ P1,
    const float* __restrict__ P2, const float* __restrict__ P3,
    const float* __restrict__ W4,   // [4][128][128]
    const float* __restrict__ bias, // [128]
    float* __restrict__ C, int reluflag) {
    __shared__ float As[16][128];  // As[k][row], 8 KB
    __shared__ float Ws[16][128];  // Ws[k][col], 8 KB
    const int tid = threadIdx.x;
    const int tx = tid & 15;        // col group: cols tx*8..tx*8+7
    const int ty = tid >> 4;        // row group: rows ty*8..ty*8+7
    const int rowbase = blockIdx.x * 128;
    // loader mapping (A): arow = tid>>1, koff = (tid&1)*8
    const int arow = tid >> 1;
    const int akoff = (tid & 1) * 8;
    const int arow_g = min(rowbase + arow, Nn - 1);
    // loader mapping (W): wk = tid>>4, wcoff = (tid&15)*8
    const int wk = tid >> 4;
    const int wcoff = (tid & 15) * 8;

    float acc[8][8];
#pragma unroll
    for (int r = 0; r < 8; ++r)
#pragma unroll
        for (int c = 0; c < 8; ++c) acc[r][c] = 0.0f;

    const float* Ps[4] = {P0, P1, P2, P3};

#pragma unroll 1
    for (int chunk = 0; chunk < 32; ++chunk) {
        const int g = chunk >> 3;
        const int kb = (chunk & 7) * 16;
        const float* P = Ps[g];
        // issue global loads into registers (overlaps previous chunk's compute)
        float4 a0 = *(const float4*)&P[(size_t)arow_g * Hd + kb + akoff];
        float4 a1 = *(const float4*)&P[(size_t)arow_g * Hd + kb + akoff + 4];
        const float* Wg = W4 + (size_t)g * Hd * Hd + (size_t)(kb + wk) * Hd;
        float4 w0 = *(const float4*)&Wg[wcoff];
        float4 w1 = *(const float4*)&Wg[wcoff + 4];
        __syncthreads();  // prev chunk's compute done before overwrite
        // store A transposed: As[k][row]
        As[akoff + 0][arow] = a0.x;
        As[akoff + 1][arow] = a0.y;
        As[akoff + 2][arow] = a0.z;
        As[akoff + 3][arow] = a0.w;
        As[akoff + 4][arow] = a1.x;
        As[akoff + 5][arow] = a1.y;
        As[akoff + 6][arow] = a1.z;
        As[akoff + 7][arow] = a1.w;
        *(float4*)&Ws[wk][wcoff] = w0;
        *(float4*)&Ws[wk][wcoff + 4] = w1;
        __syncthreads();
#pragma unroll
        for (int kk = 0; kk < 16; ++kk) {
            float4 x0 = *(const float4*)&As[kk][ty * 8];
            float4 x1 = *(const float4*)&As[kk][ty * 8 + 4];
            float4 y0 = *(const float4*)&Ws[kk][tx * 8];
            float4 y1 = *(const float4*)&Ws[kk][tx * 8 + 4];
            float av[8] = {x0.x, x0.y, x0.z, x0.w, x1.x, x1.y, x1.z, x1.w};
            float bv[8] = {y0.x, y0.y, y0.z, y0.w, y1.x, y1.y, y1.z, y1.w};
#pragma unroll
            for (int r = 0; r < 8; ++r)
#pragma unroll
                for (int c = 0; c < 8; ++c) acc[r][c] += av[r] * bv[c];
        }
    }
    // epilogue: + bias, optional relu, store
    float4 b0 = *(const float4*)&bias[tx * 8];
    float4 b1 = *(const float4*)&bias[tx * 8 + 4];
    float bb[8] = {b0.x, b0.y, b0.z, b0.w, b1.x, b1.y, b1.z, b1.w};
#pragma unroll
    for (int r = 0; r < 8; ++r) {
        int grow = rowbase + ty * 8 + r;
        if (grow < Nn) {
            float v[8];
#pragma unroll
            for (int c = 0; c < 8; ++c) {
                float t = acc[r][c] + bb[c];
                v[c] = reluflag ? fmaxf(t, 0.0f) : t;
            }
            *(float4*)&C[(size_t)grow * Hd + tx * 8] = make_float4(v[0], v[1], v[2], v[3]);
            *(float4*)&C[(size_t)grow * Hd + tx * 8 + 4] = make_float4(v[4], v[5], v[6], v[7]);
        }
    }
}

// p_out[i] = sum over incoming edges of w[e] * p_in[src[e]]; wave per node.
__global__ void hop_kernel(const float* __restrict__ pin, float* __restrict__ pout,
                           const int* __restrict__ starts, const int* __restrict__ src_s,
                           const float* __restrict__ w_s) {
    int lane = threadIdx.x & 63;
    int wid = (blockIdx.x * blockDim.x + threadIdx.x) >> 6;
    int nw = (gridDim.x * blockDim.x) >> 6;
    for (int node = wid; node < Nn; node += nw) {
        int s0 = starts[node], s1 = starts[node + 1];
        float ax = 0.0f, ay = 0.0f;
        int slot = s0;
        for (; slot + 4 <= s1; slot += 4) {
            int r0 = src_s[slot], r1 = src_s[slot + 1], r2 = src_s[slot + 2], r3 = src_s[slot + 3];
            float w0 = w_s[slot], w1 = w_s[slot + 1], w2v = w_s[slot + 2], w3 = w_s[slot + 3];
            float2 v0 = *(const float2*)&pin[r0 * Hd + 2 * lane];
            float2 v1 = *(const float2*)&pin[r1 * Hd + 2 * lane];
            float2 v2 = *(const float2*)&pin[r2 * Hd + 2 * lane];
            float2 v3 = *(const float2*)&pin[r3 * Hd + 2 * lane];
            ax += w0 * v0.x + w1 * v1.x + w2v * v2.x + w3 * v3.x;
            ay += w0 * v0.y + w1 * v1.y + w2v * v2.y + w3 * v3.y;
        }
        for (; slot < s1; ++slot) {
            int r0 = src_s[slot];
            float w0 = w_s[slot];
            float2 v0 = *(const float2*)&pin[r0 * Hd + 2 * lane];
            ax += w0 * v0.x;
            ay += w0 * v0.y;
        }
        *(float2*)&pout[node * Hd + 2 * lane] = make_float2(ax, ay);
    }
}

__global__ void out_kernel(const float* __restrict__ hin, const float* __restrict__ oW,
                           const float* __restrict__ ob, float* __restrict__ y) {
    __shared__ float w[256];
    __shared__ float bb[2];
    w[threadIdx.x] = oW[threadIdx.x & 255];
    if (threadIdx.x < 2) bb[threadIdx.x] = ob[threadIdx.x];
    __syncthreads();
    int i = blockIdx.x * blockDim.x + threadIdx.x;
    if (i < Nn) {
        float a0 = bb[0], a1 = bb[1];
#pragma unroll
        for (int k = 0; k < Hd; k += 4) {
            float4 hv = *(const float4*)&hin[i * Hd + k];
            a0 += hv.x * w[2 * k] + hv.y * w[2 * k + 2] + hv.z * w[2 * k + 4] + hv.w * w[2 * k + 6];
            a1 += hv.x * w[2 * k + 1] + hv.y * w[2 * k + 3] + hv.z * w[2 * k + 5] + hv.w * w[2 * k + 7];
        }
        *(float2*)&y[i * 2] = make_float2(a0, a1);
    }
}

extern "C" void kernel_launch(void* const* d_in, const int* in_sizes, int n_in,
                              void* d_out, int out_size, void* d_ws, size_t ws_size,
                              hipStream_t stream) {
    const float* x    = (const float*)d_in[0];
    const int*   ei   = (const int*)d_in[1];
    const float* ea   = (const float*)d_in[2];
    const float* eW1  = (const float*)d_in[3];
    const float* eb1  = (const float*)d_in[4];
    const float* eW2  = (const float*)d_in[5];
    const float* eb2  = (const float*)d_in[6];
    const float* tagW = (const float*)d_in[7];
    const float* tagb = (const float*)d_in[8];
    const float* oW   = (const float*)d_in[9];
    const float* ob   = (const float*)d_in[10];
    float* y = (float*)d_out;
    const int* row = ei;        // source
    const int* col = ei + Ee;   // target

    char* wp = (char*)d_ws;
    auto carve = [&](size_t bytes) -> char* {
        char* p = wp;
        wp += (bytes + 15) & ~(size_t)15;
        return p;
    };
    int* deg     = (int*)carve((size_t)2 * Nn * 4);  // deg | cnt adjacent
    int* cnt     = deg + Nn;
    int* starts  = (int*)carve((size_t)(Nn + 1) * 4);
    float* dinv  = (float*)carve((size_t)Nn * 4);
    int* eid_s   = (int*)carve((size_t)Ee * 4);
    int* src_s   = (int*)carve((size_t)Ee * 4);
    float* w_s   = (float*)carve((size_t)Ee * 4);
    float* hbuf  = (float*)carve((size_t)Nn * Hd * 4);
    float* obuf  = (float*)carve((size_t)Nn * Hd * 4);
    float* pb0   = (float*)carve((size_t)Nn * Hd * 4);
    float* pb1   = (float*)carve((size_t)Nn * Hd * 4);
    float* pb2   = (float*)carve((size_t)Nn * Hd * 4);

    zero_int_kernel<<<400, 256, 0, stream>>>(deg, 2 * Nn);
    count_kernel<<<(Ee + 255) / 256, 256, 0, stream>>>(col, deg);
    scan_kernel<<<1, 1024, 0, stream>>>(deg, starts, dinv);
    fill_kernel<<<(Ee + 255) / 256, 256, 0, stream>>>(row, col, starts, cnt, dinv,
                                                      eid_s, src_s, w_s);
    edge_mlp_kernel<<<1024, 256, 0, stream>>>(x, ea, starts, eid_s, src_s,
                                              eW1, eb1, eW2, eb2, hbuf);

    const int gemm_grid = (Nn + 127) / 128;
    for (int l = 0; l < Ld; ++l) {
        const float* Wl = tagW + (size_t)l * (Kd + 1) * Hd * Hd;
        hop_kernel<<<12500, 256, 0, stream>>>(hbuf, pb0, starts, src_s, w_s);
        hop_kernel<<<12500, 256, 0, stream>>>(pb0, pb1, starts, src_s, w_s);
        hop_kernel<<<12500, 256, 0, stream>>>(pb1, pb2, starts, src_s, w_s);
        tag_gemm_kernel<<<gemm_grid, 256, 0, stream>>>(hbuf, pb0, pb1, pb2, Wl,
                                                       tagb + l * Hd, obuf,
                                                       (l < Ld - 1) ? 1 : 0);
        float* t = hbuf; hbuf = obuf; obuf = t;
    }
    out_kernel<<<(Nn + 255) / 256, 256, 0, stream>>>(hbuf, oW, ob, y);
}

// Round 3
// 1390.704 us; speedup vs baseline: 14.9276x; 1.4389x over previous
//
#include <hip/hip_runtime.h>

#define Nn 50000
#define Ee 600000
#define Hd 128
#define Ld 4
#define Kd 3

__global__ void zero_int_kernel(int* __restrict__ p, int n) {
    int i = blockIdx.x * blockDim.x + threadIdx.x;
    int stride = gridDim.x * blockDim.x;
    for (; i < n; i += stride) p[i] = 0;
}

__global__ void count_kernel(const int* __restrict__ col, int* __restrict__ deg) {
    int e = blockIdx.x * blockDim.x + threadIdx.x;
    if (e < Ee) atomicAdd(&deg[col[e]], 1);
}

// Single-block exclusive scan over deg -> starts[N+1]; also dinv = deg^-1/2.
__global__ void scan_kernel(const int* __restrict__ deg, int* __restrict__ starts,
                            float* __restrict__ dinv) {
    __shared__ int buf[1024];
    __shared__ int carry;
    if (threadIdx.x == 0) carry = 0;
    __syncthreads();
    for (int base = 0; base < Nn; base += 1024) {
        int i = base + threadIdx.x;
        int v = (i < Nn) ? deg[i] : 0;
        if (i < Nn) dinv[i] = (v > 0) ? rsqrtf((float)v) : 0.0f;
        buf[threadIdx.x] = v;
        __syncthreads();
        for (int off = 1; off < 1024; off <<= 1) {
            int t = (threadIdx.x >= off) ? buf[threadIdx.x - off] : 0;
            __syncthreads();
            buf[threadIdx.x] += t;
            __syncthreads();
        }
        if (i < Nn) starts[i] = carry + buf[threadIdx.x] - v;  // exclusive
        __syncthreads();
        if (threadIdx.x == 1023) carry += buf[1023];
        __syncthreads();
    }
    if (threadIdx.x == 0) starts[Nn] = carry;
}

__global__ void fill_kernel(const int* __restrict__ row, const int* __restrict__ col,
                            const int* __restrict__ starts, int* __restrict__ cnt,
                            const float* __restrict__ dinv,
                            int* __restrict__ eid_s, int* __restrict__ src_s,
                            float* __restrict__ w_s) {
    int e = blockIdx.x * blockDim.x + threadIdx.x;
    if (e < Ee) {
        int c = col[e], r = row[e];
        int slot = starts[c] + atomicAdd(&cnt[c], 1);
        eid_s[slot] = e;
        src_s[slot] = r;
        w_s[slot] = dinv[r] * dinv[c];
    }
}

// Layer-1-only edge pass: t[i] = sum over incoming edges of relu(cat(x_i,x_j,e)@W1+b1).
// (W2 is linear, so it is applied AFTER aggregation: h = t@W2 + deg*b2.)
// One wave per target node; W1 lives in 36 VGPRs/lane; no LDS.
__global__ __launch_bounds__(256) void edge_l1_kernel(
    const float* __restrict__ x, const float* __restrict__ ea,
    const int* __restrict__ starts, const int* __restrict__ eid_s,
    const int* __restrict__ src_s,
    const float* __restrict__ eW1, const float* __restrict__ eb1,
    float* __restrict__ tout) {
    int lane = threadIdx.x & 63;
    float w1x[18], w1y[18];
#pragma unroll
    for (int j = 0; j < 18; ++j) {
        w1x[j] = eW1[j * Hd + lane];
        w1y[j] = eW1[j * Hd + lane + 64];
    }
    float b1x = eb1[lane], b1y = eb1[lane + 64];
    int wid = (blockIdx.x * 256 + threadIdx.x) >> 6;
    int nw = (gridDim.x * 256) >> 6;
    for (int node = wid; node < Nn; node += nw) {
        int s0 = starts[node], s1 = starts[node + 1];
        // target-node part of layer 1 is loop-invariant: fold into the bias
        float prex = b1x, prey = b1y;
#pragma unroll
        for (int j = 0; j < 7; ++j) {
            float xv = x[node * 7 + j];
            prex += xv * w1x[j];
            prey += xv * w1y[j];
        }
        float accx = 0.0f, accy = 0.0f;
        int slot = s0;
        for (; slot + 2 <= s1; slot += 2) {
            int srcA = src_s[slot], srcB = src_s[slot + 1];
            int eA = eid_s[slot], eB = eid_s[slot + 1];
            float4 evA = *(const float4*)&ea[eA * 4];
            float4 evB = *(const float4*)&ea[eB * 4];
            float a0 = prex, a1 = prey, c0 = prex, c1 = prey;
#pragma unroll
            for (int j = 0; j < 7; ++j) {
                float xa = x[srcA * 7 + j];
                float xb = x[srcB * 7 + j];
                a0 += xa * w1x[7 + j];
                a1 += xa * w1y[7 + j];
                c0 += xb * w1x[7 + j];
                c1 += xb * w1y[7 + j];
            }
            a0 += evA.x * w1x[14] + evA.y * w1x[15] + evA.z * w1x[16] + evA.w * w1x[17];
            a1 += evA.x * w1y[14] + evA.y * w1y[15] + evA.z * w1y[16] + evA.w * w1y[17];
            c0 += evB.x * w1x[14] + evB.y * w1x[15] + evB.z * w1x[16] + evB.w * w1x[17];
            c1 += evB.x * w1y[14] + evB.y * w1y[15] + evB.z * w1y[16] + evB.w * w1y[17];
            accx += fmaxf(a0, 0.0f) + fmaxf(c0, 0.0f);
            accy += fmaxf(a1, 0.0f) + fmaxf(c1, 0.0f);
        }
        for (; slot < s1; ++slot) {
            int src = src_s[slot];
            int e = eid_s[slot];
            float a0 = prex, a1 = prey;
#pragma unroll
            for (int j = 0; j < 7; ++j) {
                float xv = x[src * 7 + j];
                a0 += xv * w1x[7 + j];
                a1 += xv * w1y[7 + j];
            }
            float4 ev = *(const float4*)&ea[e * 4];
            a0 += ev.x * w1x[14] + ev.y * w1x[15] + ev.z * w1x[16] + ev.w * w1x[17];
            a1 += ev.x * w1y[14] + ev.y * w1y[15] + ev.z * w1y[16] + ev.w * w1y[17];
            accx += fmaxf(a0, 0.0f);
            accy += fmaxf(a1, 0.0f);
        }
        tout[node * Hd + lane] = accx;
        tout[node * Hd + lane + 64] = accy;
    }
}

// Fused multi-source GEMM: C = sum_g Ps[g]@W[g] + bias (+deg[i]*bias if rowdeg).
// 128x128 block tile, BK=16, 256 threads, 8x8 micro-tile per thread.
// Column micro-tile split {tx*4..+3, tx*4+64..+67} -> Ws lane-stride 4 floats
// -> 2-way LDS aliasing only (free per m136). As transposed, broadcast reads.
__global__ __launch_bounds__(256, 3) void tag_gemm_kernel(
    const float* __restrict__ P0, const float* __restrict__ P1,
    const float* __restrict__ P2, const float* __restrict__ P3,
    const float* __restrict__ W4,   // [nsrc][128][128]
    const float* __restrict__ bias, // [128]
    const int* __restrict__ rowdeg, // nullable: bias scaled by deg[row]
    float* __restrict__ C, int nsrc, int reluflag) {
    __shared__ float As[16][128];  // As[k][row], 8 KB
    __shared__ float Ws[16][128];  // Ws[k][col], 8 KB
    const int tid = threadIdx.x;
    const int tx = tid & 15;        // cols tx*4..tx*4+3 and tx*4+64..tx*4+67
    const int ty = tid >> 4;        // rows ty*8..ty*8+7
    const int rowbase = blockIdx.x * 128;
    const int arow = tid >> 1;
    const int akoff = (tid & 1) * 8;
    const int arow_g = min(rowbase + arow, Nn - 1);
    const int wk = tid >> 4;
    const int wcoff = (tid & 15) * 8;

    float acc[8][8];
#pragma unroll
    for (int r = 0; r < 8; ++r)
#pragma unroll
        for (int c = 0; c < 8; ++c) acc[r][c] = 0.0f;

    const float* Ps[4] = {P0, P1, P2, P3};
    const int nchunks = nsrc * 8;

#pragma unroll 1
    for (int chunk = 0; chunk < nchunks; ++chunk) {
        const int g = chunk >> 3;
        const int kb = (chunk & 7) * 16;
        const float* P = Ps[g];
        float4 a0 = *(const float4*)&P[(size_t)arow_g * Hd + kb + akoff];
        float4 a1 = *(const float4*)&P[(size_t)arow_g * Hd + kb + akoff + 4];
        const float* Wg = W4 + (size_t)g * Hd * Hd + (size_t)(kb + wk) * Hd;
        float4 w0 = *(const float4*)&Wg[wcoff];
        float4 w1 = *(const float4*)&Wg[wcoff + 4];
        __syncthreads();
        As[akoff + 0][arow] = a0.x;
        As[akoff + 1][arow] = a0.y;
        As[akoff + 2][arow] = a0.z;
        As[akoff + 3][arow] = a0.w;
        As[akoff + 4][arow] = a1.x;
        As[akoff + 5][arow] = a1.y;
        As[akoff + 6][arow] = a1.z;
        As[akoff + 7][arow] = a1.w;
        *(float4*)&Ws[wk][wcoff] = w0;
        *(float4*)&Ws[wk][wcoff + 4] = w1;
        __syncthreads();
#pragma unroll
        for (int kk = 0; kk < 16; ++kk) {
            float4 x0 = *(const float4*)&As[kk][ty * 8];
            float4 x1 = *(const float4*)&As[kk][ty * 8 + 4];
            float4 y0 = *(const float4*)&Ws[kk][tx * 4];
            float4 y1 = *(const float4*)&Ws[kk][tx * 4 + 64];
            float av[8] = {x0.x, x0.y, x0.z, x0.w, x1.x, x1.y, x1.z, x1.w};
            float bv[8] = {y0.x, y0.y, y0.z, y0.w, y1.x, y1.y, y1.z, y1.w};
#pragma unroll
            for (int r = 0; r < 8; ++r)
#pragma unroll
                for (int c = 0; c < 8; ++c) acc[r][c] += av[r] * bv[c];
        }
    }
    // epilogue: + bias (optionally scaled per-row by deg), optional relu, store
    float4 b0 = *(const float4*)&bias[tx * 4];
    float4 b1 = *(const float4*)&bias[tx * 4 + 64];
    float bb[8] = {b0.x, b0.y, b0.z, b0.w, b1.x, b1.y, b1.z, b1.w};
#pragma unroll
    for (int r = 0; r < 8; ++r) {
        int grow = rowbase + ty * 8 + r;
        if (grow < Nn) {
            float bscale = rowdeg ? (float)rowdeg[grow] : 1.0f;
            float v[8];
#pragma unroll
            for (int c = 0; c < 8; ++c) {
                float t = acc[r][c] + bscale * bb[c];
                v[c] = reluflag ? fmaxf(t, 0.0f) : t;
            }
            *(float4*)&C[(size_t)grow * Hd + tx * 4] = make_float4(v[0], v[1], v[2], v[3]);
            *(float4*)&C[(size_t)grow * Hd + tx * 4 + 64] = make_float4(v[4], v[5], v[6], v[7]);
        }
    }
}

// p_out[i] = sum over incoming edges of w[e] * p_in[src[e]]; wave per node.
__global__ void hop_kernel(const float* __restrict__ pin, float* __restrict__ pout,
                           const int* __restrict__ starts, const int* __restrict__ src_s,
                           const float* __restrict__ w_s) {
    int lane = threadIdx.x & 63;
    int wid = (blockIdx.x * blockDim.x + threadIdx.x) >> 6;
    int nw = (gridDim.x * blockDim.x) >> 6;
    for (int node = wid; node < Nn; node += nw) {
        int s0 = starts[node], s1 = starts[node + 1];
        float ax = 0.0f, ay = 0.0f;
        int slot = s0;
        for (; slot + 4 <= s1; slot += 4) {
            int r0 = src_s[slot], r1 = src_s[slot + 1], r2 = src_s[slot + 2], r3 = src_s[slot + 3];
            float w0 = w_s[slot], w1 = w_s[slot + 1], w2v = w_s[slot + 2], w3 = w_s[slot + 3];
            float2 v0 = *(const float2*)&pin[r0 * Hd + 2 * lane];
            float2 v1 = *(const float2*)&pin[r1 * Hd + 2 * lane];
            float2 v2 = *(const float2*)&pin[r2 * Hd + 2 * lane];
            float2 v3 = *(const float2*)&pin[r3 * Hd + 2 * lane];
            ax += w0 * v0.x + w1 * v1.x + w2v * v2.x + w3 * v3.x;
            ay += w0 * v0.y + w1 * v1.y + w2v * v2.y + w3 * v3.y;
        }
        for (; slot < s1; ++slot) {
            int r0 = src_s[slot];
            float w0 = w_s[slot];
            float2 v0 = *(const float2*)&pin[r0 * Hd + 2 * lane];
            ax += w0 * v0.x;
            ay += w0 * v0.y;
        }
        *(float2*)&pout[node * Hd + 2 * lane] = make_float2(ax, ay);
    }
}

__global__ void out_kernel(const float* __restrict__ hin, const float* __restrict__ oW,
                           const float* __restrict__ ob, float* __restrict__ y) {
    __shared__ float w[256];
    __shared__ float bb[2];
    w[threadIdx.x] = oW[threadIdx.x & 255];
    if (threadIdx.x < 2) bb[threadIdx.x] = ob[threadIdx.x];
    __syncthreads();
    int i = blockIdx.x * blockDim.x + threadIdx.x;
    if (i < Nn) {
        float a0 = bb[0], a1 = bb[1];
#pragma unroll
        for (int k = 0; k < Hd; k += 4) {
            float4 hv = *(const float4*)&hin[i * Hd + k];
            a0 += hv.x * w[2 * k] + hv.y * w[2 * k + 2] + hv.z * w[2 * k + 4] + hv.w * w[2 * k + 6];
            a1 += hv.x * w[2 * k + 1] + hv.y * w[2 * k + 3] + hv.z * w[2 * k + 5] + hv.w * w[2 * k + 7];
        }
        *(float2*)&y[i * 2] = make_float2(a0, a1);
    }
}

extern "C" void kernel_launch(void* const* d_in, const int* in_sizes, int n_in,
                              void* d_out, int out_size, void* d_ws, size_t ws_size,
                              hipStream_t stream) {
    const float* x    = (const float*)d_in[0];
    const int*   ei   = (const int*)d_in[1];
    const float* ea   = (const float*)d_in[2];
    const float* eW1  = (const float*)d_in[3];
    const float* eb1  = (const float*)d_in[4];
    const float* eW2  = (const float*)d_in[5];
    const float* eb2  = (const float*)d_in[6];
    const float* tagW = (const float*)d_in[7];
    const float* tagb = (const float*)d_in[8];
    const float* oW   = (const float*)d_in[9];
    const float* ob   = (const float*)d_in[10];
    float* y = (float*)d_out;
    const int* row = ei;        // source
    const int* col = ei + Ee;   // target

    char* wp = (char*)d_ws;
    auto carve = [&](size_t bytes) -> char* {
        char* p = wp;
        wp += (bytes + 15) & ~(size_t)15;
        return p;
    };
    int* deg     = (int*)carve((size_t)2 * Nn * 4);  // deg | cnt adjacent
    int* cnt     = deg + Nn;
    int* starts  = (int*)carve((size_t)(Nn + 1) * 4);
    float* dinv  = (float*)carve((size_t)Nn * 4);
    int* eid_s   = (int*)carve((size_t)Ee * 4);
    int* src_s   = (int*)carve((size_t)Ee * 4);
    float* w_s   = (float*)carve((size_t)Ee * 4);
    float* hbuf  = (float*)carve((size_t)Nn * Hd * 4);
    float* obuf  = (float*)carve((size_t)Nn * Hd * 4);
    float* pb0   = (float*)carve((size_t)Nn * Hd * 4);
    float* pb1   = (float*)carve((size_t)Nn * Hd * 4);
    float* pb2   = (float*)carve((size_t)Nn * Hd * 4);

    zero_int_kernel<<<400, 256, 0, stream>>>(deg, 2 * Nn);
    count_kernel<<<(Ee + 255) / 256, 256, 0, stream>>>(col, deg);
    scan_kernel<<<1, 1024, 0, stream>>>(deg, starts, dinv);
    fill_kernel<<<(Ee + 255) / 256, 256, 0, stream>>>(row, col, starts, cnt, dinv,
                                                      eid_s, src_s, w_s);
    // t = per-target sum of relu(layer1)  (into obuf)
    edge_l1_kernel<<<3125, 256, 0, stream>>>(x, ea, starts, eid_s, src_s,
                                             eW1, eb1, obuf);
    // h = t @ W2 + deg*b2  (into hbuf)
    const int gemm_grid = (Nn + 127) / 128;
    tag_gemm_kernel<<<gemm_grid, 256, 0, stream>>>(obuf, nullptr, nullptr, nullptr,
                                                   eW2, eb2, deg, hbuf, 1, 0);

    for (int l = 0; l < Ld; ++l) {
        const float* Wl = tagW + (size_t)l * (Kd + 1) * Hd * Hd;
        hop_kernel<<<12500, 256, 0, stream>>>(hbuf, pb0, starts, src_s, w_s);
        hop_kernel<<<12500, 256, 0, stream>>>(pb0, pb1, starts, src_s, w_s);
        hop_kernel<<<12500, 256, 0, stream>>>(pb1, pb2, starts, src_s, w_s);
        tag_gemm_kernel<<<gemm_grid, 256, 0, stream>>>(hbuf, pb0, pb1, pb2, Wl,
                                                       tagb + l * Hd, nullptr, obuf, 4,
                                                       (l < Ld - 1) ? 1 : 0);
        float* t = hbuf; hbuf = obuf; obuf = t;
    }
    out_kernel<<<(Nn + 255) / 256, 256, 0, stream>>>(hbuf, oW, ob, y);
}